// Round 5
// baseline (91.964 us; speedup 1.0000x reference)
//
#include <hip/hip_runtime.h>
#include <hip/hip_bf16.h>

#define M_DIM 4096
#define N_DIM 4096
#define K_DIM 1024
#define NT (K_DIM / 64)   // 16 K-tiles of BK=64

typedef short short8 __attribute__((ext_vector_type(8)));
typedef unsigned short ushort8 __attribute__((ext_vector_type(8)));
typedef float f32x4 __attribute__((ext_vector_type(4)));

// fp32 -> bf16 round-to-nearest-even (bias-free over the K-sum)
__device__ __forceinline__ unsigned short f2bf_rne(float f) {
    union { float f; unsigned u; } v;
    v.f = f;
    unsigned u = v.u;
    u += 0x7FFFu + ((u >> 16) & 1u);
    return (unsigned short)(u >> 16);
}

// async global->LDS, 16B/lane. LDS dest = wave-uniform base + lane*16.
__device__ __forceinline__ void gload16(const void* g, void* l) {
    __builtin_amdgcn_global_load_lds(
        (const __attribute__((address_space(1))) void*)g,
        (__attribute__((address_space(3))) void*)l,
        16, 0, 0);
}

// ---- merged conversion: A fp32->bf16 (same layout) + B fp32 -> Bt bf16 (N x K) ----
__global__ __launch_bounds__(256) void cvt_kernel(const float* __restrict__ A,
                                                  const float* __restrict__ B,
                                                  unsigned short* __restrict__ Aw,
                                                  unsigned short* __restrict__ Bw) {
    __shared__ unsigned short tile[32][33];
    if (blockIdx.x < 2048) {
        size_t i = (size_t)blockIdx.x * 256 + threadIdx.x;
        const float4* s = (const float4*)A + i * 2;
        float4 v0 = s[0], v1 = s[1];
        ushort8 o;
        o[0] = f2bf_rne(v0.x); o[1] = f2bf_rne(v0.y);
        o[2] = f2bf_rne(v0.z); o[3] = f2bf_rne(v0.w);
        o[4] = f2bf_rne(v1.x); o[5] = f2bf_rne(v1.y);
        o[6] = f2bf_rne(v1.z); o[7] = f2bf_rne(v1.w);
        *(ushort8*)(Aw + i * 8) = o;
    } else {
        int bb = blockIdx.x - 2048;
        int bx = bb & 127, by = bb >> 7;
        int x = threadIdx.x & 31, y = threadIdx.x >> 5;
        int n0 = bx * 32, k0 = by * 32;
#pragma unroll
        for (int j = 0; j < 4; ++j)
            tile[y + j * 8][x] = f2bf_rne(B[(size_t)(k0 + y + j * 8) * N_DIM + n0 + x]);
        __syncthreads();
#pragma unroll
        for (int j = 0; j < 4; ++j)
            Bw[(size_t)(n0 + y + j * 8) * K_DIM + k0 + x] = tile[x][y + j * 8];
    }
}

// ---- 128x128x64 GEMM, 2 resident blocks/CU: C fp32 = A(bf16 MxK) * Bt(bf16 NxK) ----
// 4 waves (2Mx2N), per-wave 64x64 = acc[4][4] (64 AGPR).
// A: gload_lds into 2x16KB LDS dbuf (XOR slot swizzle). B: dwordx4 fragments
// straight from global into ping-pong regs, prefetched ONE TILE AHEAD.
// One __syncthreads per tile; k-outer MFMA (16 independent per k-step).
__global__ __launch_bounds__(256, 2) void gemm_kernel(const unsigned short* __restrict__ A,
                                                      const unsigned short* __restrict__ Bt,
                                                      float* __restrict__ C) {
    __shared__ __align__(16) unsigned short sA[2][128 * 64];   // 32 KiB

    // XCD-aware bijective swizzle: 1024 blocks, 8 XCDs, 128 tiles/XCD
    // (4 tile-rows x 32 tile-cols -> shared A panels per XCD-L2).
    int bid = blockIdx.x;
    int xcd = bid & 7, i = bid >> 3;
    int tm = xcd * 4 + (i & 3);
    int tn = i >> 2;
    int bM = tm * 128, bN = tn * 128;

    int tid = threadIdx.x;
    int wid = tid >> 6, lane = tid & 63;
    int wm = wid >> 1, wn = wid & 1;

    // A staging: per call u, wave writes 8 rows of 128B linear; swizzled source slot
    int srow = lane >> 3;                 // 0..7
    int cslot = (lane & 7) ^ srow;        // inverse-swizzled global 16B-slot
    const unsigned short* gA = A + (size_t)(bM + wid * 8 + srow) * K_DIM + cslot * 8;

#define STG4(kt, buf)                                                                  \
    _Pragma("unroll") for (int u = 0; u < 4; ++u)                                      \
        gload16(gA + (size_t)u * 32 * K_DIM + (size_t)(kt) * 64,                       \
                (char*)&sA[buf][0] + u * 4096 + wid * 1024);

    // B direct-fragment base: row bN + wn*64 + n*16 + (lane&15), 16B at k-slot lane>>4
    const unsigned short* gBs =
        Bt + (size_t)(bN + wn * 64 + (lane & 15)) * K_DIM + (lane >> 4) * 8;

#define BVLOAD(BV, kt)                                                                 \
    _Pragma("unroll") for (int n = 0; n < 4; ++n)                                      \
        _Pragma("unroll") for (int k = 0; k < 2; ++k)                                  \
            BV[n][k] = *(const short8*)(gBs + (size_t)n * 16 * K_DIM +                 \
                                        (size_t)(kt) * 64 + k * 32);

    // A fragment reads from LDS (slot XOR swizzle; row&7 == lane&7 here)
    int rA = wm * 64 + (lane & 15);
    int rslot = lane >> 4;
    int l7 = lane & 7;
#define LDA(buf, m, k) \
    (*(const short8*)&sA[buf][(rA + (m) * 16) * 64 + ((((k) * 4 + rslot) ^ l7) * 8)])

#define LDAV(BUF)                                                                      \
    _Pragma("unroll") for (int m = 0; m < 4; ++m)                                      \
        _Pragma("unroll") for (int k = 0; k < 2; ++k)                                  \
            av[m][k] = LDA(BUF, m, k);

#define MFMA32(BV)                                                                     \
    _Pragma("unroll") for (int k = 0; k < 2; ++k)                                      \
        _Pragma("unroll") for (int m = 0; m < 4; ++m)                                  \
            _Pragma("unroll") for (int n = 0; n < 4; ++n)                              \
                acc[m][n] = __builtin_amdgcn_mfma_f32_16x16x32_bf16(                   \
                    av[m][k], BV[n][k], acc[m][n], 0, 0, 0);

    f32x4 acc[4][4];
#pragma unroll
    for (int m = 0; m < 4; ++m)
#pragma unroll
        for (int n = 0; n < 4; ++n)
            acc[m][n] = (f32x4){0.f, 0.f, 0.f, 0.f};

    short8 av[4][2];
    short8 bvP[4][2], bvQ[4][2];

    // one K-tile: reads LDS buf CB + reg buf BVC; prefetches t+1 into 1-CB / BVN
#define TILE(t, CB, BVC, BVN)                                                          \
    {                                                                                  \
        if ((t) + 1 < NT) { STG4((t) + 1, 1 - (CB)) BVLOAD(BVN, (t) + 1) }             \
        LDAV(CB)                                                                       \
        __builtin_amdgcn_s_setprio(1);                                                 \
        MFMA32(BVC)                                                                    \
        __builtin_amdgcn_s_setprio(0);                                                 \
        if ((t) + 1 < NT) __syncthreads();                                             \
    }

    // prologue: stage tile 0 (LDS + B regs), drain, sync
    STG4(0, 0)
    BVLOAD(bvP, 0)
    __syncthreads();

    for (int t = 0; t < NT; t += 2) {
        TILE(t, 0, bvP, bvQ)
        TILE(t + 1, 1, bvQ, bvP)
    }

    // epilogue: C/D layout col=lane&15, row=(lane>>4)*4+r
    size_t crow = (size_t)bM + wm * 64 + ((lane >> 4) << 2);
    int ccol = bN + wn * 64 + (lane & 15);
#pragma unroll
    for (int m = 0; m < 4; ++m)
#pragma unroll
        for (int n = 0; n < 4; ++n)
#pragma unroll
            for (int r = 0; r < 4; ++r)
                C[(crow + m * 16 + r) * N_DIM + ccol + n * 16] = acc[m][n][r];
#undef STG4
#undef BVLOAD
#undef LDA
#undef LDAV
#undef MFMA32
#undef TILE
}

// ---- fallback: plain fp32 tiled GEMM (only if ws too small; exact) ----
__global__ __launch_bounds__(256) void sgemm_fb(const float* __restrict__ A,
                                                const float* __restrict__ B,
                                                float* __restrict__ C) {
    __shared__ float sA[64][17];
    __shared__ float sB[16][65];
    int tx = threadIdx.x, ty = threadIdx.y;
    int bM = blockIdx.y * 64, bN = blockIdx.x * 64;
    int t = ty * 16 + tx;
    float acc[4][4] = {};
    for (int k0 = 0; k0 < K_DIM; k0 += 16) {
        __syncthreads();
#pragma unroll
        for (int e = 0; e < 4; ++e) {
            int idx = t * 4 + e;
            int r = idx >> 4, c = idx & 15;
            sA[r][c] = A[(size_t)(bM + r) * K_DIM + k0 + c];
            int r2 = idx >> 6, c2 = idx & 63;
            sB[r2][c2] = B[(size_t)(k0 + r2) * N_DIM + bN + c2];
        }
        __syncthreads();
#pragma unroll
        for (int k = 0; k < 16; ++k) {
            float ar[4], br[4];
#pragma unroll
            for (int q = 0; q < 4; ++q) { ar[q] = sA[ty * 4 + q][k]; br[q] = sB[k][tx * 4 + q]; }
#pragma unroll
            for (int q = 0; q < 4; ++q)
#pragma unroll
                for (int w = 0; w < 4; ++w)
                    acc[q][w] += ar[q] * br[w];
        }
    }
#pragma unroll
    for (int q = 0; q < 4; ++q)
#pragma unroll
        for (int w = 0; w < 4; ++w)
            C[(size_t)(bM + ty * 4 + q) * N_DIM + bN + tx * 4 + w] = acc[q][w];
}

extern "C" void kernel_launch(void* const* d_in, const int* in_sizes, int n_in,
                              void* d_out, int out_size, void* d_ws, size_t ws_size,
                              hipStream_t stream) {
    const float* A = (const float*)d_in[0];
    const float* B = (const float*)d_in[1];
    float* C = (float*)d_out;

    size_t needA = (size_t)M_DIM * K_DIM * sizeof(unsigned short);
    size_t needB = (size_t)K_DIM * N_DIM * sizeof(unsigned short);

    if (ws_size >= needA + needB) {
        unsigned short* Aw = (unsigned short*)d_ws;
        unsigned short* Bw = Aw + (size_t)M_DIM * K_DIM;
        cvt_kernel<<<2048 + 4096, 256, 0, stream>>>(A, B, Aw, Bw);
        gemm_kernel<<<(M_DIM / 128) * (N_DIM / 128), 256, 0, stream>>>(Aw, Bw, C);
    } else {
        sgemm_fb<<<dim3(N_DIM / 64, M_DIM / 64), dim3(16, 16), 0, stream>>>(A, B, C);
    }
}

// Round 6
// 50.220 us; speedup vs baseline: 1.8312x; 1.8312x over previous
//
#include <hip/hip_runtime.h>
#include <hip/hip_bf16.h>

#define M_DIM 4096
#define N_DIM 4096
#define K_DIM 1024
#define NT (K_DIM / 64)   // 16 K-tiles of BK=64

typedef short short8 __attribute__((ext_vector_type(8)));
typedef unsigned short ushort8 __attribute__((ext_vector_type(8)));
typedef unsigned short ushort4v __attribute__((ext_vector_type(4)));
typedef float f32x4 __attribute__((ext_vector_type(4)));

// fp32 -> bf16 round-to-nearest-even (bias-free over the K-sum)
__device__ __forceinline__ unsigned short f2bf_rne(float f) {
    union { float f; unsigned u; } v;
    v.f = f;
    unsigned u = v.u;
    u += 0x7FFFu + ((u >> 16) & 1u);
    return (unsigned short)(u >> 16);
}

// async global->LDS, 16B/lane. LDS dest = wave-uniform base + lane*16.
__device__ __forceinline__ void gload16(const void* g, void* l) {
    __builtin_amdgcn_global_load_lds(
        (const __attribute__((address_space(1))) void*)g,
        (__attribute__((address_space(3))) void*)l,
        16, 0, 0);
}

// ---- merged conversion ----
// blocks 0..2047:    A fp32 -> bf16 (same M x K layout), 8 elems/thread
// blocks 2048..3071: B fp32 (K x N) -> Bt bf16 (N x K), 64x64 tile, vectorized
__global__ __launch_bounds__(256) void cvt_kernel(const float* __restrict__ A,
                                                  const float* __restrict__ B,
                                                  unsigned short* __restrict__ Aw,
                                                  unsigned short* __restrict__ Bw) {
    __shared__ unsigned short tile[64][68];   // +4 pad
    if (blockIdx.x < 2048) {
        size_t i = (size_t)blockIdx.x * 256 + threadIdx.x;
        const float4* s = (const float4*)A + i * 2;
        float4 v0 = s[0], v1 = s[1];
        ushort8 o;
        o[0] = f2bf_rne(v0.x); o[1] = f2bf_rne(v0.y);
        o[2] = f2bf_rne(v0.z); o[3] = f2bf_rne(v0.w);
        o[4] = f2bf_rne(v1.x); o[5] = f2bf_rne(v1.y);
        o[6] = f2bf_rne(v1.z); o[7] = f2bf_rne(v1.w);
        *(ushort8*)(Aw + i * 8) = o;
    } else {
        int bb = blockIdx.x - 2048;               // 0..1023
        int bn = bb & 63, bk = bb >> 6;           // 64 n-tiles x 16 k-tiles
        int n0 = bn * 64, k0 = bk * 64;
        int kr = threadIdx.x >> 4;                // 0..15
        int nc = threadIdx.x & 15;                // float4 / ushort4 chunk
#pragma unroll
        for (int p = 0; p < 4; ++p) {
            int k = kr + p * 16;
            float4 v = *(const float4*)&B[(size_t)(k0 + k) * N_DIM + n0 + nc * 4];
            ushort4v u;
            u[0] = f2bf_rne(v.x); u[1] = f2bf_rne(v.y);
            u[2] = f2bf_rne(v.z); u[3] = f2bf_rne(v.w);
            *(ushort4v*)&tile[k][nc * 4] = u;     // 8B aligned (136k + 8nc)
        }
        __syncthreads();
#pragma unroll
        for (int p = 0; p < 4; ++p) {
            int n = kr + p * 16;
            ushort4v o;
#pragma unroll
            for (int j = 0; j < 4; ++j) o[j] = tile[nc * 4 + j][n];
            *(ushort4v*)&Bw[(size_t)(n0 + n) * K_DIM + k0 + nc * 4] = o;
        }
    }
}

// ---- 256x256x64 8-phase GEMM (R2 core): C fp32 = A(bf16 MxK) * Bt(bf16 NxK) ----
// 8 waves (2Mx4N), per-wave 128x64 = acc[8][4]. LDS 128 KiB dbuf, XOR slot swizzle.
// Diffs vs R2: k-outer MFMA (indep chains); last tile barrier-less with
// interleaved C stores.
__global__ __launch_bounds__(512, 2) void gemm8_kernel(const unsigned short* __restrict__ A,
                                                       const unsigned short* __restrict__ Bt,
                                                       float* __restrict__ C) {
    __shared__ __align__(16) unsigned short lds[2][2][256 * 64];  // [buf][0=A,1=B]

    // XCD-aware bijective swizzle: 256 blocks, 8 XCDs, 32 tiles/XCD
    int bid = blockIdx.x;
    int xcd = bid & 7, ii = bid >> 3;
    int tm = xcd * 2 + (ii & 1);
    int tn = ii >> 1;
    int bM = tm * 256, bN = tn * 256;

    int tid = threadIdx.x;
    int wid = tid >> 6, lane = tid & 63;
    int wm = wid >> 2, wn = wid & 3;

    int srow = lane >> 3;
    int cslot = (lane & 7) ^ srow;      // inverse-swizzled global 16B-slot
    int stg_row = wid * 8 + srow;

    const unsigned short* gA = A + (size_t)(bM + stg_row) * K_DIM + cslot * 8;
    const unsigned short* gB = Bt + (size_t)(bN + stg_row) * K_DIM + cslot * 8;

#define STG(mat, unit, buf, kt)                                                        \
    gload16((mat ? gB : gA) + (size_t)((unit) * 64) * K_DIM + (size_t)(kt) * 64,       \
            (char*)&lds[(buf)][(mat)][0] + (unit) * 8192 + wid * 1024)

    int rA = wm * 128 + (lane & 15);
    int rB = wn * 64 + (lane & 15);
    int rslot = lane >> 4;
    int l7 = lane & 7;

#define LDA(buf, m, k) \
    (*(const short8*)&lds[(buf)][0][(rA + (m) * 16) * 64 + ((((k) * 4 + rslot) ^ l7) * 8)])
#define LDB(buf, n, k) \
    (*(const short8*)&lds[(buf)][1][(rB + (n) * 16) * 64 + ((((k) * 4 + rslot) ^ l7) * 8)])

    f32x4 acc[8][4];
#pragma unroll
    for (int m = 0; m < 8; ++m)
#pragma unroll
        for (int n = 0; n < 4; ++n)
            acc[m][n] = (f32x4){0.f, 0.f, 0.f, 0.f};

    short8 av[2][2], bv[4][2];

    // k-OUTER MFMA: 8 independent MFMAs between dependent writes to each acc
#define PHASE_MFMA(MBASE)                                                              \
    __builtin_amdgcn_s_barrier();                                                      \
    asm volatile("s_waitcnt lgkmcnt(0)" ::: "memory");                                 \
    __builtin_amdgcn_sched_barrier(0);                                                 \
    __builtin_amdgcn_s_setprio(1);                                                     \
    _Pragma("unroll") for (int k = 0; k < 2; ++k)                                      \
        _Pragma("unroll") for (int m2 = 0; m2 < 2; ++m2)                               \
            _Pragma("unroll") for (int n = 0; n < 4; ++n)                              \
                acc[(MBASE) + m2][n] = __builtin_amdgcn_mfma_f32_16x16x32_bf16(        \
                    av[m2][k], bv[n][k], acc[(MBASE) + m2][n], 0, 0, 0);               \
    __builtin_amdgcn_s_setprio(0);

#define LOAD_AV(buf, MBASE)                                                            \
    _Pragma("unroll") for (int m2 = 0; m2 < 2; ++m2)                                   \
        _Pragma("unroll") for (int k = 0; k < 2; ++k)                                  \
            av[m2][k] = LDA(buf, (MBASE) + m2, k);

    // ---- prologue: tile0 fully + tile1's first 6 units; drain to tile0 resident ----
#pragma unroll
    for (int u = 0; u < 4; ++u) { STG(1, u, 0, 0); }
#pragma unroll
    for (int u = 0; u < 4; ++u) { STG(0, u, 0, 0); }
#pragma unroll
    for (int u = 0; u < 4; ++u) { STG(1, u, 1, 1); }
    STG(0, 0, 1, 1);
    STG(0, 2, 1, 1);
    asm volatile("s_waitcnt vmcnt(6)" ::: "memory");
    __builtin_amdgcn_s_barrier();

    for (int t = 0; t < NT - 1; ++t) {
        int cur = t & 1, nxt = cur ^ 1;

        // ph0: all B frags + A m0,1 (12 ds_reads); stage t+1's A-u1,u3
#pragma unroll
        for (int n = 0; n < 4; ++n)
#pragma unroll
            for (int k = 0; k < 2; ++k)
                bv[n][k] = LDB(cur, n, k);
        LOAD_AV(cur, 0)
        STG(0, 1, nxt, t + 1); STG(0, 3, nxt, t + 1);
        PHASE_MFMA(0)
        __builtin_amdgcn_s_barrier();

        // ph1: A m2,3; stage t+2's B-u0,u1
        LOAD_AV(cur, 2)
        if (t + 2 < NT) { STG(1, 0, cur, t + 2); STG(1, 1, cur, t + 2); }
        PHASE_MFMA(2)
        __builtin_amdgcn_s_barrier();

        // ph2: A m4,5; stage t+2's B-u2,u3
        LOAD_AV(cur, 4)
        if (t + 2 < NT) { STG(1, 2, cur, t + 2); STG(1, 3, cur, t + 2); }
        PHASE_MFMA(4)
        __builtin_amdgcn_s_barrier();

        // ph3: A m6,7; stage t+2's A-u0,u2
        LOAD_AV(cur, 6)
        if (t + 2 < NT) { STG(0, 0, cur, t + 2); STG(0, 2, cur, t + 2); }
        PHASE_MFMA(6)
        // K-tile boundary: counted vmcnt -> next tile resident
        if (t < NT - 2) {
            asm volatile("s_waitcnt vmcnt(6)" ::: "memory");
        } else {
            asm volatile("s_waitcnt vmcnt(0)" ::: "memory");
        }
        __builtin_amdgcn_s_barrier();
    }

    // ---- last K-tile (t = NT-1, buf 1): no barriers; C-stores interleaved ----
    {
        size_t crow = (size_t)bM + wm * 128 + ((lane >> 4) << 2);
        int ccol = bN + wn * 64 + (lane & 15);
#pragma unroll
        for (int n = 0; n < 4; ++n)
#pragma unroll
            for (int k = 0; k < 2; ++k)
                bv[n][k] = LDB(1, n, k);
#pragma unroll
        for (int mb = 0; mb < 4; ++mb) {
            LOAD_AV(1, mb * 2)
#pragma unroll
            for (int k = 0; k < 2; ++k)
#pragma unroll
                for (int m2 = 0; m2 < 2; ++m2)
#pragma unroll
                    for (int n = 0; n < 4; ++n)
                        acc[mb * 2 + m2][n] = __builtin_amdgcn_mfma_f32_16x16x32_bf16(
                            av[m2][k], bv[n][k], acc[mb * 2 + m2][n], 0, 0, 0);
#pragma unroll
            for (int m2 = 0; m2 < 2; ++m2)
#pragma unroll
                for (int n = 0; n < 4; ++n)
#pragma unroll
                    for (int r = 0; r < 4; ++r)
                        C[(crow + (mb * 2 + m2) * 16 + r) * N_DIM + ccol + n * 16] =
                            acc[mb * 2 + m2][n][r];
        }
    }
#undef STG
#undef LDA
#undef LDB
#undef PHASE_MFMA
#undef LOAD_AV
}

// ---- fallback: plain fp32 tiled GEMM (only if ws too small; exact) ----
__global__ __launch_bounds__(256) void sgemm_fb(const float* __restrict__ A,
                                                const float* __restrict__ B,
                                                float* __restrict__ C) {
    __shared__ float sA[64][17];
    __shared__ float sB[16][65];
    int tx = threadIdx.x, ty = threadIdx.y;
    int bM = blockIdx.y * 64, bN = blockIdx.x * 64;
    int t = ty * 16 + tx;
    float acc[4][4] = {};
    for (int k0 = 0; k0 < K_DIM; k0 += 16) {
        __syncthreads();
#pragma unroll
        for (int e = 0; e < 4; ++e) {
            int idx = t * 4 + e;
            int r = idx >> 4, c = idx & 15;
            sA[r][c] = A[(size_t)(bM + r) * K_DIM + k0 + c];
            int r2 = idx >> 6, c2 = idx & 63;
            sB[r2][c2] = B[(size_t)(k0 + r2) * N_DIM + bN + c2];
        }
        __syncthreads();
#pragma unroll
        for (int k = 0; k < 16; ++k) {
            float ar[4], br[4];
#pragma unroll
            for (int q = 0; q < 4; ++q) { ar[q] = sA[ty * 4 + q][k]; br[q] = sB[k][tx * 4 + q]; }
#pragma unroll
            for (int q = 0; q < 4; ++q)
#pragma unroll
                for (int w = 0; w < 4; ++w)
                    acc[q][w] += ar[q] * br[w];
        }
    }
#pragma unroll
    for (int q = 0; q < 4; ++q)
#pragma unroll
        for (int w = 0; w < 4; ++w)
            C[(size_t)(bM + ty * 4 + q) * N_DIM + bN + tx * 4 + w] = acc[q][w];
}

extern "C" void kernel_launch(void* const* d_in, const int* in_sizes, int n_in,
                              void* d_out, int out_size, void* d_ws, size_t ws_size,
                              hipStream_t stream) {
    const float* A = (const float*)d_in[0];
    const float* B = (const float*)d_in[1];
    float* C = (float*)d_out;

    size_t needA = (size_t)M_DIM * K_DIM * sizeof(unsigned short);
    size_t needB = (size_t)K_DIM * N_DIM * sizeof(unsigned short);

    if (ws_size >= needA + needB) {
        unsigned short* Aw = (unsigned short*)d_ws;
        unsigned short* Bw = Aw + (size_t)M_DIM * K_DIM;
        cvt_kernel<<<2048 + 1024, 256, 0, stream>>>(A, B, Aw, Bw);
        gemm8_kernel<<<(M_DIM / 256) * (N_DIM / 256), 512, 0, stream>>>(Aw, Bw, C);
    } else {
        sgemm_fb<<<dim3(N_DIM / 64, M_DIM / 64), dim3(16, 16), 0, stream>>>(A, B, C);
    }
}

// Round 7
// 48.892 us; speedup vs baseline: 1.8810x; 1.0272x over previous
//
#include <hip/hip_runtime.h>
#include <hip/hip_bf16.h>

#define M_DIM 4096
#define N_DIM 4096
#define K_DIM 1024
#define NT (K_DIM / 64)   // 16 K-tiles of BK=64

typedef short short8 __attribute__((ext_vector_type(8)));
typedef unsigned short ushort8 __attribute__((ext_vector_type(8)));
typedef unsigned short ushort4v __attribute__((ext_vector_type(4)));
typedef float f32x4 __attribute__((ext_vector_type(4)));

// fp32 -> bf16 round-to-nearest-even (bias-free over the K-sum)
__device__ __forceinline__ unsigned short f2bf_rne(float f) {
    union { float f; unsigned u; } v;
    v.f = f;
    unsigned u = v.u;
    u += 0x7FFFu + ((u >> 16) & 1u);
    return (unsigned short)(u >> 16);
}

// async global->LDS, 16B/lane. LDS dest = wave-uniform base + lane*16.
__device__ __forceinline__ void gload16(const void* g, void* l) {
    __builtin_amdgcn_global_load_lds(
        (const __attribute__((address_space(1))) void*)g,
        (__attribute__((address_space(3))) void*)l,
        16, 0, 0);
}

// ---- merged conversion ----
__global__ __launch_bounds__(256) void cvt_kernel(const float* __restrict__ A,
                                                  const float* __restrict__ B,
                                                  unsigned short* __restrict__ Aw,
                                                  unsigned short* __restrict__ Bw) {
    __shared__ unsigned short tile[64][68];   // +4 pad
    if (blockIdx.x < 2048) {
        size_t i = (size_t)blockIdx.x * 256 + threadIdx.x;
        const float4* s = (const float4*)A + i * 2;
        float4 v0 = s[0], v1 = s[1];
        ushort8 o;
        o[0] = f2bf_rne(v0.x); o[1] = f2bf_rne(v0.y);
        o[2] = f2bf_rne(v0.z); o[3] = f2bf_rne(v0.w);
        o[4] = f2bf_rne(v1.x); o[5] = f2bf_rne(v1.y);
        o[6] = f2bf_rne(v1.z); o[7] = f2bf_rne(v1.w);
        *(ushort8*)(Aw + i * 8) = o;
    } else {
        int bb = blockIdx.x - 2048;               // 0..1023
        int bn = bb & 63, bk = bb >> 6;           // 64 n-tiles x 16 k-tiles
        int n0 = bn * 64, k0 = bk * 64;
        int kr = threadIdx.x >> 4;                // 0..15
        int nc = threadIdx.x & 15;
#pragma unroll
        for (int p = 0; p < 4; ++p) {
            int k = kr + p * 16;
            float4 v = *(const float4*)&B[(size_t)(k0 + k) * N_DIM + n0 + nc * 4];
            ushort4v u;
            u[0] = f2bf_rne(v.x); u[1] = f2bf_rne(v.y);
            u[2] = f2bf_rne(v.z); u[3] = f2bf_rne(v.w);
            *(ushort4v*)&tile[k][nc * 4] = u;
        }
        __syncthreads();
#pragma unroll
        for (int p = 0; p < 4; ++p) {
            int n = kr + p * 16;
            ushort4v o;
#pragma unroll
            for (int j = 0; j < 4; ++j) o[j] = tile[nc * 4 + j][n];
            *(ushort4v*)&Bw[(size_t)(n0 + n) * K_DIM + k0 + nc * 4] = o;
        }
    }
}

// ---- 256x256x64 GEMM, balanced 8-subphase schedule ----
// 8 waves (2Mx4N), per-wave 128x64 = acc[8][4]. LDS 128 KiB dbuf, XOR swizzle.
// Subphase q: MFMA 8 (m-pair x 4n x 1k) using regs read in q-1; issue 3 ds_reads
// for q+1 (A m-pair + 1 B frag); STG budget 8 gloads/tile. Sync: 3 barriers
// (end-q3 +vmcnt(2), end-q4, end-q7 +vmcnt(6)) per tile.
__global__ __launch_bounds__(512, 2) void gemm8_kernel(const unsigned short* __restrict__ A,
                                                       const unsigned short* __restrict__ Bt,
                                                       float* __restrict__ C) {
    __shared__ __align__(16) unsigned short lds[2][2][256 * 64];  // [buf][0=A,1=B]

    int bid = blockIdx.x;
    int xcd = bid & 7, ii = bid >> 3;
    int tm = xcd * 2 + (ii & 1);
    int tn = ii >> 1;
    int bM = tm * 256, bN = tn * 256;

    int tid = threadIdx.x;
    int wid = tid >> 6, lane = tid & 63;
    int wm = wid >> 2, wn = wid & 3;

    int srow = lane >> 3;
    int cslot = (lane & 7) ^ srow;
    int stg_row = wid * 8 + srow;

    const unsigned short* gA = A + (size_t)(bM + stg_row) * K_DIM + cslot * 8;
    const unsigned short* gB = Bt + (size_t)(bN + stg_row) * K_DIM + cslot * 8;

#define STG(mat, unit, buf, kt)                                                        \
    gload16((mat ? gB : gA) + (size_t)((unit) * 64) * K_DIM + (size_t)(kt) * 64,       \
            (char*)&lds[(buf)][(mat)][0] + (unit) * 8192 + wid * 1024)

    int rA = wm * 128 + (lane & 15);
    int rB = wn * 64 + (lane & 15);
    int rslot = lane >> 4;
    int l7 = lane & 7;

#define LDA(buf, m, k) \
    (*(const short8*)&lds[(buf)][0][(rA + (m) * 16) * 64 + ((((k) * 4 + rslot) ^ l7) * 8)])
#define LDB(buf, n, k) \
    (*(const short8*)&lds[(buf)][1][(rB + (n) * 16) * 64 + ((((k) * 4 + rslot) ^ l7) * 8)])

    f32x4 acc[8][4];
#pragma unroll
    for (int m = 0; m < 8; ++m)
#pragma unroll
        for (int n = 0; n < 4; ++n)
            acc[m][n] = (f32x4){0.f, 0.f, 0.f, 0.f};

    short8 avP[2], avQ[2];     // m-pair ping-pong
    short8 bv0[4], bv1[4];     // k0 / k1 B fragments

#define SB0 __builtin_amdgcn_sched_barrier(0);
#define BAR                                    \
    __builtin_amdgcn_sched_barrier(0);         \
    __builtin_amdgcn_s_barrier();              \
    __builtin_amdgcn_sched_barrier(0);

#define RD_AV(AV, BUF, MB, KK)                 \
    AV[0] = LDA(BUF, (MB), KK);                \
    AV[1] = LDA(BUF, (MB) + 1, KK);

#define MFMAQ(AV, BV, MB)                                                              \
    __builtin_amdgcn_s_setprio(1);                                                     \
    _Pragma("unroll") for (int m2 = 0; m2 < 2; ++m2)                                   \
        _Pragma("unroll") for (int n = 0; n < 4; ++n)                                  \
            acc[(MB) + m2][n] = __builtin_amdgcn_mfma_f32_16x16x32_bf16(               \
                AV[m2], BV[n], acc[(MB) + m2][n], 0, 0, 0);                            \
    __builtin_amdgcn_s_setprio(0);

    // steady tile: HT2 = (t+2 < NT) compile-path, VME = boundary vmcnt string
#define TILE(t, CB, NB, HT2, VME)                                                      \
    {                                                                                  \
        /* q0 */                                                                       \
        RD_AV(avQ, CB, 2, 0) bv1[0] = LDB(CB, 0, 1);                                   \
        STG(0, 1, NB, (t) + 1);                                                        \
        MFMAQ(avP, bv0, 0) SB0                                                         \
        /* q1 */                                                                       \
        RD_AV(avP, CB, 4, 0) bv1[1] = LDB(CB, 1, 1);                                   \
        STG(0, 3, NB, (t) + 1);                                                        \
        MFMAQ(avQ, bv0, 2) SB0                                                         \
        /* q2 */                                                                       \
        RD_AV(avQ, CB, 6, 0) bv1[2] = LDB(CB, 2, 1);                                   \
        MFMAQ(avP, bv0, 4) SB0                                                         \
        /* q3 */                                                                       \
        RD_AV(avP, CB, 0, 1) bv1[3] = LDB(CB, 3, 1);                                   \
        MFMAQ(avQ, bv0, 6)                                                             \
        asm volatile("s_waitcnt vmcnt(2)" ::: "memory");                               \
        BAR                                                                            \
        /* q4 */                                                                       \
        RD_AV(avQ, CB, 2, 1) bv0[0] = LDB(NB, 0, 0);                                   \
        if (HT2) { STG(1, 0, CB, (t) + 2); }                                           \
        MFMAQ(avP, bv1, 0)                                                             \
        BAR                                                                            \
        /* q5 */                                                                       \
        RD_AV(avP, CB, 4, 1) bv0[1] = LDB(NB, 1, 0);                                   \
        if (HT2) { STG(1, 1, CB, (t) + 2); STG(0, 0, CB, (t) + 2); }                   \
        MFMAQ(avQ, bv1, 2) SB0                                                         \
        /* q6 */                                                                       \
        RD_AV(avQ, CB, 6, 1) bv0[2] = LDB(NB, 2, 0);                                   \
        if (HT2) { STG(1, 2, CB, (t) + 2); STG(0, 2, CB, (t) + 2); }                   \
        MFMAQ(avP, bv1, 4) SB0                                                         \
        /* q7 */                                                                       \
        RD_AV(avP, NB, 0, 0) bv0[3] = LDB(NB, 3, 0);                                   \
        if (HT2) { STG(1, 3, CB, (t) + 2); }                                           \
        MFMAQ(avQ, bv1, 6)                                                             \
        asm volatile("s_waitcnt " VME ::: "memory");                                   \
        BAR                                                                            \
    }

    // ---- prologue: t0 all 8 units + t1's 6 (steady q4-7 order) ----
    STG(1, 0, 0, 0); STG(1, 1, 0, 0); STG(1, 2, 0, 0); STG(1, 3, 0, 0);
    STG(0, 0, 0, 0); STG(0, 1, 0, 0); STG(0, 2, 0, 0); STG(0, 3, 0, 0);
    STG(1, 0, 1, 1); STG(1, 1, 1, 1); STG(0, 0, 1, 1);
    STG(1, 2, 1, 1); STG(0, 2, 1, 1); STG(1, 3, 1, 1);
    asm volatile("s_waitcnt vmcnt(6)" ::: "memory");
    BAR
    // pre-reads for tile0 q0
    bv0[0] = LDB(0, 0, 0); bv0[1] = LDB(0, 1, 0);
    bv0[2] = LDB(0, 2, 0); bv0[3] = LDB(0, 3, 0);
    RD_AV(avP, 0, 0, 0)
    SB0

    for (int t = 0; t < NT - 2; t += 2) {
        TILE(t, 0, 1, true, "vmcnt(6)")
        TILE(t + 1, 1, 0, true, "vmcnt(6)")
    }
    TILE(NT - 2, 0, 1, false, "vmcnt(0)")

    // ---- last tile (buf 1): barrier-free, fused C stores ----
    {
        size_t crow = (size_t)bM + wm * 128 + ((lane >> 4) << 2);
        int ccol = bN + wn * 64 + (lane & 15);
#define ST2(MB)                                                                        \
        _Pragma("unroll") for (int m2 = 0; m2 < 2; ++m2)                               \
            _Pragma("unroll") for (int n = 0; n < 4; ++n)                              \
                _Pragma("unroll") for (int r = 0; r < 4; ++r)                          \
                    C[(crow + ((MB) + m2) * 16 + r) * N_DIM + ccol + n * 16] =         \
                        acc[(MB) + m2][n][r];
        /* q0 */ RD_AV(avQ, 1, 2, 0) bv1[0] = LDB(1, 0, 1); MFMAQ(avP, bv0, 0) SB0
        /* q1 */ RD_AV(avP, 1, 4, 0) bv1[1] = LDB(1, 1, 1); MFMAQ(avQ, bv0, 2) SB0
        /* q2 */ RD_AV(avQ, 1, 6, 0) bv1[2] = LDB(1, 2, 1); MFMAQ(avP, bv0, 4) SB0
        /* q3 */ RD_AV(avP, 1, 0, 1) bv1[3] = LDB(1, 3, 1); MFMAQ(avQ, bv0, 6) SB0
        /* q4 */ RD_AV(avQ, 1, 2, 1) MFMAQ(avP, bv1, 0) ST2(0) SB0
        /* q5 */ RD_AV(avP, 1, 4, 1) MFMAQ(avQ, bv1, 2) ST2(2) SB0
        /* q6 */ RD_AV(avQ, 1, 6, 1) MFMAQ(avP, bv1, 4) ST2(4) SB0
        /* q7 */ MFMAQ(avQ, bv1, 6) ST2(6)
#undef ST2
    }
#undef STG
#undef LDA
#undef LDB
#undef SB0
#undef BAR
#undef RD_AV
#undef MFMAQ
#undef TILE
}

// ---- fallback: plain fp32 tiled GEMM (only if ws too small; exact) ----
__global__ __launch_bounds__(256) void sgemm_fb(const float* __restrict__ A,
                                                const float* __restrict__ B,
                                                float* __restrict__ C) {
    __shared__ float sA[64][17];
    __shared__ float sB[16][65];
    int tx = threadIdx.x, ty = threadIdx.y;
    int bM = blockIdx.y * 64, bN = blockIdx.x * 64;
    int t = ty * 16 + tx;
    float acc[4][4] = {};
    for (int k0 = 0; k0 < K_DIM; k0 += 16) {
        __syncthreads();
#pragma unroll
        for (int e = 0; e < 4; ++e) {
            int idx = t * 4 + e;
            int r = idx >> 4, c = idx & 15;
            sA[r][c] = A[(size_t)(bM + r) * K_DIM + k0 + c];
            int r2 = idx >> 6, c2 = idx & 63;
            sB[r2][c2] = B[(size_t)(k0 + r2) * N_DIM + bN + c2];
        }
        __syncthreads();
#pragma unroll
        for (int k = 0; k < 16; ++k) {
            float ar[4], br[4];
#pragma unroll
            for (int q = 0; q < 4; ++q) { ar[q] = sA[ty * 4 + q][k]; br[q] = sB[k][tx * 4 + q]; }
#pragma unroll
            for (int q = 0; q < 4; ++q)
#pragma unroll
                for (int w = 0; w < 4; ++w)
                    acc[q][w] += ar[q] * br[w];
        }
    }
#pragma unroll
    for (int q = 0; q < 4; ++q)
#pragma unroll
        for (int w = 0; w < 4; ++w)
            C[(size_t)(bM + ty * 4 + q) * N_DIM + bN + tx * 4 + w] = acc[q][w];
}

extern "C" void kernel_launch(void* const* d_in, const int* in_sizes, int n_in,
                              void* d_out, int out_size, void* d_ws, size_t ws_size,
                              hipStream_t stream) {
    const float* A = (const float*)d_in[0];
    const float* B = (const float*)d_in[1];
    float* C = (float*)d_out;

    size_t needA = (size_t)M_DIM * K_DIM * sizeof(unsigned short);
    size_t needB = (size_t)K_DIM * N_DIM * sizeof(unsigned short);

    if (ws_size >= needA + needB) {
        unsigned short* Aw = (unsigned short*)d_ws;
        unsigned short* Bw = Aw + (size_t)M_DIM * K_DIM;
        cvt_kernel<<<2048 + 1024, 256, 0, stream>>>(A, B, Aw, Bw);
        gemm8_kernel<<<(M_DIM / 256) * (N_DIM / 256), 512, 0, stream>>>(Aw, Bw, C);
    } else {
        sgemm_fb<<<dim3(N_DIM / 64, M_DIM / 64), dim3(16, 16), 0, stream>>>(A, B, C);
    }
}